// Round 20
// baseline (41.148 us; speedup 1.0000x reference)
//
#include <hip/hip_runtime.h>

// ConvTranspose4d via bf16 MFMA (R20 = R19 + LSTR=48 bank-free stride + 16-wave blocks).
// Gather: out[co,f,od,oh,ow] = sum_{ci,i,kd,kh,kw} x[ci,f+i,id,ih,iw]*W[ci,co,i,kd,kh,kw]
// Stack: R16 E/O fold (one MFMA/K-step, A rows 0-7 even-ow / 8-15 odd-ow weights);
//   R17 LDS staging (TA wall); R18 bf16-packed LDS words; R19 od-pair sharing.
// R20a: LDS row stride 52->48. Bank starts of the 4 read-quarters become
//   (b, b+16, b+16, b) -> 2-way aliasing = FREE (m136). 52 gave 3-4-way mixes (1.8M).
// R20b: block = od-pair x 8-oh-group = 16 waves (1024 thr). Staged rows per od-pair
//   2x144 -> 240 (t-span 5); barriers/fixed costs halve; blocks 3456 -> 1728.
//   LDS 240*48*4 = 46080 B -> 2 blocks/CU = 32 waves (full occupancy).
// Row layout: row = ((ci*3+i)*2 + e)*5 + t ; e=0 plane p+1 (kd=0), e=1 plane p.
// Math order unchanged -> absmax bit-identical 0.0078125.

typedef float  f32x4  __attribute__((ext_vector_type(4)));
typedef float  f4a    __attribute__((ext_vector_type(4)));
typedef short  bf16x8 __attribute__((ext_vector_type(8)));
typedef unsigned int u32;
typedef u32    u32x4  __attribute__((ext_vector_type(4)));

namespace {
constexpr int T_ = 8, D_ = 24, H_ = 48, W_ = 48;
constexpr int TO = 6, DO_ = 47, HO = 95, WO = 95;
constexpr int XCS = T_ * D_ * H_ * W_;
constexpr int XFS = D_ * H_ * W_;
constexpr int XDS = H_ * W_;
constexpr long OCS = (long)TO * DO_ * HO * WO;
constexpr int OFS = DO_ * HO * WO;
constexpr int ODS = HO * WO;

constexpr int AG[4] = {24, 12, 12, 8};
constexpr int AOFF[4] = {0, 3072, 4608, 6144};         // shorts; total 7168 = 14 KB
constexpr int LSTR = 48;                               // LDS row stride (u32) - R20a
constexpr int ESTR = 5;                                // t-slots per (gg,e) row group
constexpr int GSTR = 10;                               // rows per gg

__global__ __launch_bounds__(256) void pack_kernel(const float* __restrict__ w,
                                                   unsigned short* __restrict__ A) {
  const int tid = blockIdx.x * 256 + threadIdx.x;
  const int nthr = gridDim.x * 256;
  const int NDs[4] = {2, 2, 1, 1}, NHs[4] = {2, 1, 2, 1}, KR[4] = {192, 96, 96, 48};
  for (int c = 0; c < 4; ++c) {
    const int cnt = AG[c] * 128;                       // [g][r(16)][j(8)] shorts
    for (int e = tid; e < cnt; e += nthr) {
      const int j = e & 7, r = (e >> 3) & 15, g = e >> 7;
      const int k = g * 8 + j;
      float v = 0.f;
      if (k < KR[c]) {
        int gg, a = 0, b = 0, cc;
        if (c == 0)      { gg = g;                a = (j >> 2) & 1; b = (j >> 1) & 1; cc = j & 1; }
        else if (c == 1) { gg = 2 * g + (j >> 2); a = (j >> 1) & 1;                   cc = j & 1; }
        else if (c == 2) { gg = 2 * g + (j >> 2); b = (j >> 1) & 1;                   cc = j & 1; }
        else             { gg = 4 * g + (j >> 1);                                     cc = j & 1; }
        if (gg < 24) {
          const int ci = gg / 3, i = gg - 3 * (gg / 3);
          const int kd = (NDs[c] == 2) ? (a ? 2 : 0) : 1;
          const int kh = (NHs[c] == 2) ? (b ? 2 : 0) : 1;
          const int co = r & 7;
          int kw = (r < 8) ? (cc == 0 ? 1 : -1) : (cc == 0 ? 2 : 0);
          if (kw >= 0) v = w[ci * 648 + co * 81 + i * 27 + kd * 9 + kh * 3 + kw];
        }
      }
      u32 u = __float_as_uint(v);
      u += 0x7FFFu + ((u >> 16) & 1u);                 // RNE to bf16
      A[AOFF[c] + e] = (unsigned short)(u >> 16);
    }
  }
}

template<int PD, int PH>
__device__ __forceinline__ void wave_body(
    const u32* __restrict__ lds, const unsigned short* __restrict__ A,
    float* __restrict__ out, int f, int od, int oh, int ihb, int lane)
{
  constexpr int CLS = (PD && PH) ? 0 : PD ? 1 : PH ? 2 : 3;
  constexpr int NSTEP = (CLS == 0) ? 6 : (CLS == 3) ? 2 : 3;
  const int c15 = lane & 15, q = lane >> 4;
  const int th = ((oh + PH) >> 1) - ihb;               // top h-row (0..4)

  bf16x8 af[NSTEP];
  {
    const unsigned short* Ap = A + AOFF[CLS] + c15 * 8;
    #pragma unroll
    for (int s = 0; s < NSTEP; ++s)
      af[s] = *reinterpret_cast<const bf16x8*>(Ap + (s * 4 + q) * 128);
  }

  f32x4 acc[3];
  #pragma unroll
  for (int b = 0; b < 3; ++b) acc[b] = {0, 0, 0, 0};

  #pragma unroll
  for (int blk = 0; blk < 3; ++blk) {
    const int n = blk * 16 + c15;
    #pragma unroll
    for (int s = 0; s < NSTEP; ++s) {
      const int G = s * 4 + q;
      int rows[4];
      if constexpr (CLS == 0) {                        // gg=G; d = (e, tdel)
        const int base = G * GSTR;
        rows[0] = base + th;        rows[1] = base + th - 1;
        rows[2] = base + ESTR + th; rows[3] = base + ESTR + th - 1;
      } else if constexpr (CLS == 1) {                 // d = (gpar, e)
        const int b0 = (2 * G) * GSTR, b1 = (2 * G + 1) * GSTR;
        rows[0] = b0 + th; rows[1] = b0 + ESTR + th;
        rows[2] = b1 + th; rows[3] = b1 + ESTR + th;
      } else if constexpr (CLS == 2) {                 // d = (gpar, tdel); e=1 plane
        const int b0 = (2 * G) * GSTR + ESTR, b1 = (2 * G + 1) * GSTR + ESTR;
        rows[0] = b0 + th; rows[1] = b0 + th - 1;
        rows[2] = b1 + th; rows[3] = b1 + th - 1;
      } else {                                         // d = gg&3 (clamped); e=1 plane
        #pragma unroll
        for (int d = 0; d < 4; ++d) {
          int gg = 4 * G + d; gg = (gg > 23) ? 23 : gg;
          rows[d] = gg * GSTR + ESTR + th;
        }
      }
      const u32x4 ue = {lds[rows[0] * LSTR + n], lds[rows[1] * LSTR + n],
                        lds[rows[2] * LSTR + n], lds[rows[3] * LSTR + n]};
      acc[blk] = __builtin_amdgcn_mfma_f32_16x16x32_bf16(af[s], __builtin_bit_cast(bf16x8, ue), acc[blk], 0, 0, 0);
    }
  }

  // D rows 0-7 = co (even ow), 8-15 = co (odd ow); row = q*4+j, col = c15.
  const int isO = (q >= 2);
  const int co0 = (q & 1) * 4;
  #pragma unroll
  for (int blk = 0; blk < 3; ++blk) {
    const int ow = blk * 32 + 2 * c15 + isO;
    if (ow < 95) {
      const long ob = (long)f * OFS + (long)od * ODS + (long)oh * HO + ow;
      #pragma unroll
      for (int j = 0; j < 4; ++j)
        out[(long)(co0 + j) * OCS + ob] = acc[blk][j];
    }
  }
}

constexpr int NBLK = 6 * 24 * 12;                      // f x od-pair x og(8 oh rows) = 1728

__global__ __launch_bounds__(1024) void convt4d_kernel(
    const float* __restrict__ x, const unsigned short* __restrict__ A,
    float* __restrict__ out)
{
  __shared__ u32 lds[240 * LSTR];                      // 46080 B

  constexpr int qq = NBLK / 8;                         // 216 (NBLK%8==0)
  const int bid = blockIdx.x;
  const int L = (bid & 7) * qq + (bid >> 3);           // bijective XCD swizzle
  const int og = L % 12;
  const int rest = L / 12;
  const int odp = rest % 24, f = rest / 24;            // od pair: {2*odp, 2*odp+1}

  const int tid = threadIdx.x;
  const int ihb = og * 4;
  const int idp = odp + 1;                             // e=0 plane = p+1, e=1 plane = p

  // stage 240-row union PRE-PACKED: lds[row*LSTR+n] = bf(x[n]) | bf(x[n+1])<<16
  // row = ((ci*3+i)*2 + e)*5 + t
  for (int c = tid; c < 240 * 12; c += 1024) {
    const int row = c / 12, ch = c % 12;
    const int t = row % 5;
    const int r2 = row / 5;
    const int e = r2 & 1;
    const int r3 = r2 >> 1;
    const int i = r3 % 3, ci = r3 / 3;
    int plane = idp - e; if (plane > 23) plane = 23;   // odp=23,e=0: unused, clamp OOB
    int ih = ihb + t; if (ih > 47) ih = 47;            // og=11 t=4: unused, clamp
    const float* src = x + ci * XCS + (f + i) * XFS + plane * XDS + ih * W_ + ch * 4;
    const f4a v = *reinterpret_cast<const f4a*>(src);
    const float v4 = (ch == 11) ? 0.f : src[4];        // x[48] slot must be 0 (n=47 pair)
    const u32 b0 = __float_as_uint(v.x), b1 = __float_as_uint(v.y);
    const u32 b2 = __float_as_uint(v.z), b3 = __float_as_uint(v.w);
    const u32 b4 = __float_as_uint(v4);
    const u32x4 pk = {__builtin_amdgcn_perm(b1, b0, 0x07060302u),
                      __builtin_amdgcn_perm(b2, b1, 0x07060302u),
                      __builtin_amdgcn_perm(b3, b2, 0x07060302u),
                      __builtin_amdgcn_perm(b4, b3, 0x07060302u)};
    *reinterpret_cast<u32x4*>(&lds[row * LSTR + ch * 4]) = pk;  // 16B-aligned (48*4%16==0)
  }
  __syncthreads();

  const int w = tid >> 6, lane = tid & 63;
  const int half = w >> 3;                             // 0: od=2p (pd0), 1: od=2p+1 (pd1)
  const int od = 2 * odp + half;
  if (od > 46) return;                                 // odp=23 pd1 half: no od=47
  int oh = og * 8 + (w & 7);
  if (oh > 94) oh = 93;                                // og=11,w&7=7: dup of w&7=5 (benign)
  if (half) {
    if (oh & 1) wave_body<1, 1>(lds, A, out, f, od, oh, ihb, lane);
    else        wave_body<1, 0>(lds, A, out, f, od, oh, ihb, lane);
  } else {
    if (oh & 1) wave_body<0, 1>(lds, A, out, f, od, oh, ihb, lane);
    else        wave_body<0, 0>(lds, A, out, f, od, oh, ihb, lane);
  }
}
}  // namespace

extern "C" void kernel_launch(void* const* d_in, const int* in_sizes, int n_in,
                              void* d_out, int out_size, void* d_ws, size_t ws_size,
                              hipStream_t stream) {
  const float* x = (const float*)d_in[0];
  const float* w = (const float*)d_in[1];
  float* out = (float*)d_out;
  unsigned short* A = (unsigned short*)d_ws;           // 7168 shorts = 14 KB
  hipLaunchKernelGGL(pack_kernel, dim3(8), dim3(256), 0, stream, w, A);
  hipLaunchKernelGGL(convt4d_kernel, dim3(NBLK), dim3(1024), 0, stream, x, A, out);
}

// Round 21
// 35.684 us; speedup vs baseline: 1.1531x; 1.1531x over previous
//
#include <hip/hip_runtime.h>

// ConvTranspose4d via bf16 MFMA (R21 = R19 + LSTR=48 + const-offset LDS reads).
// Gather: out[co,f,od,oh,ow] = sum_{ci,i,kd,kh,kw} x[ci,f+i,id,ih,iw]*W[ci,co,i,kd,kh,kw]
// Stack: R16 E/O fold (one MFMA/K-step); R17 LDS staging; R18 bf16-packed words;
//   R19 od-pair 8-wave blocks (best, 37.7us). R20's 16-wave merge REVERTED (41.1us:
//   doubled barrier span + 2-blocks/CU residency; also violated single-variable rule).
// R21a: LSTR 52->48. Read-quad bank starts become (row%2)*16 -> CLS0/1/2 quads pair
//   2x2-way = FREE (m136); 52 gave 3-4-way mixes (1.8M conflicts).
// R21b: reads rewritten as base[{const}*LSTR] -- per-class compile-time offset quads
//   {1,0,4,3}/{0,3,6,9}/{1,0,7,6}/{0,6,12,18} -> ds_read immediates (ds_read2 fusion),
//   deleting per-read v_lshl_add address math. CLS3 clamp moved to base (g4=min(4G,20);
//   those K-groups have A=0 so any in-range row is fine).
// Math order unchanged -> absmax bit-identical 0.0078125.

typedef float  f32x4  __attribute__((ext_vector_type(4)));
typedef float  f4a    __attribute__((ext_vector_type(4)));
typedef short  bf16x8 __attribute__((ext_vector_type(8)));
typedef unsigned int u32;
typedef u32    u32x4  __attribute__((ext_vector_type(4)));

namespace {
constexpr int T_ = 8, D_ = 24, H_ = 48, W_ = 48;
constexpr int TO = 6, DO_ = 47, HO = 95, WO = 95;
constexpr int XCS = T_ * D_ * H_ * W_;
constexpr int XFS = D_ * H_ * W_;
constexpr int XDS = H_ * W_;
constexpr long OCS = (long)TO * DO_ * HO * WO;
constexpr int OFS = DO_ * HO * WO;
constexpr int ODS = HO * WO;

constexpr int AG[4] = {24, 12, 12, 8};
constexpr int AOFF[4] = {0, 3072, 4608, 6144};         // shorts; total 7168 = 14 KB
constexpr int LSTR = 48;                               // LDS row stride (u32) - R21a

__global__ __launch_bounds__(256) void pack_kernel(const float* __restrict__ w,
                                                   unsigned short* __restrict__ A) {
  const int tid = blockIdx.x * 256 + threadIdx.x;
  const int nthr = gridDim.x * 256;
  const int NDs[4] = {2, 2, 1, 1}, NHs[4] = {2, 1, 2, 1}, KR[4] = {192, 96, 96, 48};
  for (int c = 0; c < 4; ++c) {
    const int cnt = AG[c] * 128;                       // [g][r(16)][j(8)] shorts
    for (int e = tid; e < cnt; e += nthr) {
      const int j = e & 7, r = (e >> 3) & 15, g = e >> 7;
      const int k = g * 8 + j;
      float v = 0.f;
      if (k < KR[c]) {
        int gg, a = 0, b = 0, cc;
        if (c == 0)      { gg = g;                a = (j >> 2) & 1; b = (j >> 1) & 1; cc = j & 1; }
        else if (c == 1) { gg = 2 * g + (j >> 2); a = (j >> 1) & 1;                   cc = j & 1; }
        else if (c == 2) { gg = 2 * g + (j >> 2); b = (j >> 1) & 1;                   cc = j & 1; }
        else             { gg = 4 * g + (j >> 1);                                     cc = j & 1; }
        if (gg < 24) {
          const int ci = gg / 3, i = gg - 3 * (gg / 3);
          const int kd = (NDs[c] == 2) ? (a ? 2 : 0) : 1;
          const int kh = (NHs[c] == 2) ? (b ? 2 : 0) : 1;
          const int co = r & 7;
          int kw = (r < 8) ? (cc == 0 ? 1 : -1) : (cc == 0 ? 2 : 0);
          if (kw >= 0) v = w[ci * 648 + co * 81 + i * 27 + kd * 9 + kh * 3 + kw];
        }
      }
      u32 u = __float_as_uint(v);
      u += 0x7FFFu + ((u >> 16) & 1u);                 // RNE to bf16
      A[AOFF[c] + e] = (unsigned short)(u >> 16);
    }
  }
}

template<int PD, int PH>
__device__ __forceinline__ void wave_body(
    const u32* __restrict__ lds, const unsigned short* __restrict__ A,
    float* __restrict__ out, int f, int od, int oh, int ihb, int lane)
{
  constexpr int CLS = (PD && PH) ? 0 : PD ? 1 : PH ? 2 : 3;
  constexpr int NSTEP = (CLS == 0) ? 6 : (CLS == 3) ? 2 : 3;
  const int c15 = lane & 15, q = lane >> 4;
  const int th = ((oh + PH) >> 1) - ihb;               // top h-row (0..2)

  bf16x8 af[NSTEP];
  {
    const unsigned short* Ap = A + AOFF[CLS] + c15 * 8;
    #pragma unroll
    for (int s = 0; s < NSTEP; ++s)
      af[s] = *reinterpret_cast<const bf16x8*>(Ap + (s * 4 + q) * 128);
  }

  f32x4 acc[3];
  #pragma unroll
  for (int b = 0; b < 3; ++b) acc[b] = {0, 0, 0, 0};

  // shared layout: row = ((ci*3+i)*2 + e)*3 + t ; e=0 -> plane p+1 (kd=0), e=1 -> p
  // R21b: one runtime base per step + compile-time row-offset quad (ds imm offsets).
  #pragma unroll
  for (int blk = 0; blk < 3; ++blk) {
    const int n = blk * 16 + c15;
    #pragma unroll
    for (int s = 0; s < NSTEP; ++s) {
      const int G = s * 4 + q;
      const u32* base;
      int o0, o1, o2, o3;                              // compile-time after unroll
      if constexpr (CLS == 0) {                        // rows: G*6 + {th,th-1,3+th,2+th}
        base = lds + (G * 6 + th - 1) * LSTR + n;
        o0 = 1; o1 = 0; o2 = 4; o3 = 3;
      } else if constexpr (CLS == 1) {                 // rows: 2G*6 + {th,3+th,6+th,9+th}
        base = lds + (2 * G * 6 + th) * LSTR + n;
        o0 = 0; o1 = 3; o2 = 6; o3 = 9;
      } else if constexpr (CLS == 2) {                 // rows: 2G*6+3 + {th,th-1,6+th,5+th}
        base = lds + (2 * G * 6 + 3 + th - 1) * LSTR + n;
        o0 = 1; o1 = 0; o2 = 7; o3 = 6;
      } else {                                         // rows: (g4+d)*6+3+th; g4 clamp ok:
        const int g4 = (G > 5) ? 20 : 4 * G;           // G>5 -> A==0 (k>=48), any row fine
        base = lds + (g4 * 6 + 3 + th) * LSTR + n;
        o0 = 0; o1 = 6; o2 = 12; o3 = 18;
      }
      const u32x4 ue = {base[o0 * LSTR], base[o1 * LSTR], base[o2 * LSTR], base[o3 * LSTR]};
      acc[blk] = __builtin_amdgcn_mfma_f32_16x16x32_bf16(af[s], __builtin_bit_cast(bf16x8, ue), acc[blk], 0, 0, 0);
    }
  }

  // D rows 0-7 = co (even ow), 8-15 = co (odd ow); row = q*4+j, col = c15.
  const int isO = (q >= 2);
  const int co0 = (q & 1) * 4;
  #pragma unroll
  for (int blk = 0; blk < 3; ++blk) {
    const int ow = blk * 32 + 2 * c15 + isO;
    if (ow < 95) {
      const long ob = (long)f * OFS + (long)od * ODS + (long)oh * HO + ow;
      #pragma unroll
      for (int j = 0; j < 4; ++j)
        out[(long)(co0 + j) * OCS + ob] = acc[blk][j];
    }
  }
}

constexpr int NBLK = 6 * 24 * 24;                      // f x od-pair x og = 3456

__global__ __launch_bounds__(512) void convt4d_kernel(
    const float* __restrict__ x, const unsigned short* __restrict__ A,
    float* __restrict__ out)
{
  __shared__ u32 lds[144 * LSTR];                      // 27648 B

  constexpr int qq = NBLK / 8;                         // 432 (NBLK%8==0)
  const int bid = blockIdx.x;
  const int L = (bid & 7) * qq + (bid >> 3);           // bijective XCD swizzle
  const int og = L % 24;
  const int rest = L / 24;
  const int odp = rest % 24, f = rest / 24;            // od pair: {2*odp, 2*odp+1}

  const int tid = threadIdx.x;
  const int ihb = og * 2;
  const int idp = odp + 1;                             // e=0 plane = p+1, e=1 plane = p

  // stage 144-row union PRE-PACKED: lds[row*LSTR+n] = bf(x[n]) | bf(x[n+1])<<16
  // row = ((ci*3+i)*2 + e)*3 + t
  for (int c = tid; c < 144 * 12; c += 512) {
    const int row = c / 12, ch = c % 12;
    const int t = row % 3;
    const int r2 = row / 3;
    const int e = r2 & 1;
    const int r3 = r2 >> 1;
    const int i = r3 % 3, ci = r3 / 3;
    int plane = idp - e; if (plane > 23) plane = 23;   // odp=23,e=0: unused, clamp OOB
    int ih = ihb + t; if (ih > 47) ih = 47;            // og=23 t=2: unused, clamp
    const float* src = x + ci * XCS + (f + i) * XFS + plane * XDS + ih * W_ + ch * 4;
    const f4a v = *reinterpret_cast<const f4a*>(src);
    const float v4 = (ch == 11) ? 0.f : src[4];        // x[48] slot must be 0 (n=47 pair)
    const u32 b0 = __float_as_uint(v.x), b1 = __float_as_uint(v.y);
    const u32 b2 = __float_as_uint(v.z), b3 = __float_as_uint(v.w);
    const u32 b4 = __float_as_uint(v4);
    const u32x4 pk = {__builtin_amdgcn_perm(b1, b0, 0x07060302u),
                      __builtin_amdgcn_perm(b2, b1, 0x07060302u),
                      __builtin_amdgcn_perm(b3, b2, 0x07060302u),
                      __builtin_amdgcn_perm(b4, b3, 0x07060302u)};
    *reinterpret_cast<u32x4*>(&lds[row * LSTR + ch * 4]) = pk;  // 16B-aligned (48*4%16==0)
  }
  __syncthreads();

  const int w = tid >> 6, lane = tid & 63;
  const int half = w >> 2;                             // 0: od=2p (pd0), 1: od=2p+1 (pd1)
  const int od = 2 * odp + half;
  if (od > 46) return;                                 // odp=23 pd1 half: no od=47
  int oh = og * 4 + (w & 3);
  if (oh > 94) oh = 93;                                // og=23,w&3=3: dup of w&3=1 (benign)
  if (half) {
    if (oh & 1) wave_body<1, 1>(lds, A, out, f, od, oh, ihb, lane);
    else        wave_body<1, 0>(lds, A, out, f, od, oh, ihb, lane);
  } else {
    if (oh & 1) wave_body<0, 1>(lds, A, out, f, od, oh, ihb, lane);
    else        wave_body<0, 0>(lds, A, out, f, od, oh, ihb, lane);
  }
}
}  // namespace

extern "C" void kernel_launch(void* const* d_in, const int* in_sizes, int n_in,
                              void* d_out, int out_size, void* d_ws, size_t ws_size,
                              hipStream_t stream) {
  const float* x = (const float*)d_in[0];
  const float* w = (const float*)d_in[1];
  float* out = (float*)d_out;
  unsigned short* A = (unsigned short*)d_ws;           // 7168 shorts = 14 KB
  hipLaunchKernelGGL(pack_kernel, dim3(8), dim3(256), 0, stream, w, A);
  hipLaunchKernelGGL(convt4d_kernel, dim3(NBLK), dim3(512), 0, stream, x, A, out);
}